// Round 4
// baseline (1301.564 us; speedup 1.0000x reference)
//
#include <hip/hip_runtime.h>

#define NPTS 100000
#define INC 256
#define WID 104
#define WSC 416
#define KOFF 27
#define EPSV 1e-5f

typedef unsigned short u16;
typedef float f32x4 __attribute__((ext_vector_type(4)));
typedef short s16x8 __attribute__((ext_vector_type(8)));

__device__ __forceinline__ u16 f2bf(float f) {
  unsigned u = __builtin_bit_cast(unsigned, f);
  u += 0x7FFFu + ((u >> 16) & 1u);
  return (u16)(u >> 16);
}
__device__ __forceinline__ float bf2f(u16 h) {
  unsigned u = ((unsigned)h) << 16;
  return __builtin_bit_cast(float, u);
}
__device__ __forceinline__ void mfma16(f32x4& d, s16x8 a, s16x8 b) {
  asm("v_mfma_f32_16x16x32_bf16 %0, %1, %2, %0" : "+v"(d) : "v"(a), "v"(b));
}
__device__ __forceinline__ void rawbar() {
  __builtin_amdgcn_s_barrier();
  __builtin_amdgcn_sched_barrier(0);
}

// stats region layout (floats): [8 banks][sum C][sumsq C], then [scale C][shift C]
#define ST1_OFF 0
#define STC0_OFF 7488
#define STC1_OFF 9360
#define STC2_OFF 11232
#define ST3_OFF 13104
#define ST_TOTAL 17712

// SPX padded row stride (elems)
#define SPAD 128

// ---------------- weight prep ----------------
__global__ __launch_bounds__(256) void k_prep_w1w3(const float* __restrict__ w1,
    const float* __restrict__ w3, u16* __restrict__ w1t, u16* __restrict__ w3t) {
  int i = blockIdx.x * 256 + threadIdx.x;
  if (i < 416 * 256) {
    int n = i >> 8, k = i & 255;
    w1t[i] = f2bf(w1[(size_t)k * WSC + n]);
  } else if (i < 2 * 416 * 256) {
    int o = i - 416 * 256;
    int n = o / WSC, k = o - n * WSC;
    w3t[o] = f2bf(w3[(size_t)k * INC + n]);
  }
}

// WCF: fragment-major conv weights. Per (branch,k): 28 frags (ct*4+kc) x 64 lanes x 8 elems.
// frag(ct,kc) lane l elem j = Wc[b][k][kin][n], n = ct*16+(l&15), kin = kc*32+(l>>4)*8+j (0 if OOB)
__global__ __launch_bounds__(256) void k_prep_wc(const float* __restrict__ wc,
                                                 u16* __restrict__ wcf) {
  __shared__ float w[WID * WID];
  int blk = blockIdx.x, t = threadIdx.x;   // blk = b*27 + k
  const float* s = wc + (size_t)blk * WID * WID;
  for (int i = t; i < WID * WID; i += 256) w[i] = s[i];
  __syncthreads();
  u16* d = wcf + (size_t)blk * 28 * 512;
  for (int task = t; task < 28 * 64; task += 256) {
    int frag = task >> 6, l = task & 63;
    int ct = frag >> 2, kc = frag & 3;
    int n = ct * 16 + (l & 15);
    int kb = kc * 32 + (l >> 4) * 8;
    s16x8 h;
#pragma unroll
    for (int j = 0; j < 8; ++j) {
      int kin = kb + j;
      float v = (kin < WID && n < WID) ? w[kin * WID + n] : 0.f;
      h[j] = (short)f2bf(v);
    }
    *(s16x8*)(d + (size_t)task * 8) = h;
  }
}

__global__ void k_init(float* __restrict__ st, u16* __restrict__ spxp) {
  const s16x8 hz = {0, 0, 0, 0, 0, 0, 0, 0};
  int i = blockIdx.x * 256 + threadIdx.x;
  if (i < ST_TOTAL) st[i] = 0.f;
  // zero pad chunks 13..15 of every row (incl. row NPTS)
  for (int task = i; task < (NPTS + 1) * 3; task += gridDim.x * 256) {
    int r = task / 3, c = task - 3 * r;
    *(s16x8*)(spxp + (size_t)r * SPAD + (13 + c) * 8) = hz;
  }
  // zero data chunks of row NPTS
  if (blockIdx.x == 0 && threadIdx.x < 13)
    *(s16x8*)(spxp + (size_t)NPTS * SPAD + threadIdx.x * 8) = hz;
}

// ---------------- x -> bf16 ----------------
__global__ __launch_bounds__(256) void k_xbf(const float* __restrict__ x,
                                             u16* __restrict__ xb) {
  const int total = NPTS * INC / 8;
  for (int i = blockIdx.x * 256 + threadIdx.x; i < total; i += gridDim.x * 256) {
    const f32x4* s = (const f32x4*)(x + (size_t)i * 8);
    f32x4 v0 = s[0], v1 = s[1];
    s16x8 h;
#pragma unroll
    for (int j = 0; j < 4; ++j) { h[j] = (short)f2bf(v0[j]); h[4 + j] = (short)f2bf(v1[j]); }
    *(s16x8*)(xb + (size_t)i * 8) = h;
  }
}

// ---------------- GEMM1: xb[N,256] @ W1 -> Y1[N,416] bf16 raw + banked col stats ----------------
__global__ __launch_bounds__(256) void k_gemm1(const u16* __restrict__ xb,
    const u16* __restrict__ w1t, u16* __restrict__ y1, float* __restrict__ stats) {
  __shared__ char Al[128 * 128];
  __shared__ char Bl[112 * 128];
  const int t = threadIdx.x, rowbase = blockIdx.x * 128, cb = blockIdx.y;
  const int lane = t & 63, wv = t >> 6, lr = lane & 15, lg = lane >> 4;
  const f32x4 fz = {0.f, 0.f, 0.f, 0.f};
  const s16x8 hz = {0, 0, 0, 0, 0, 0, 0, 0};
  f32x4 acc[2][7];
#pragma unroll
  for (int i = 0; i < 2; ++i)
#pragma unroll
    for (int j = 0; j < 7; ++j) acc[i][j] = fz;
  s16x8 pa[4], pb[4];

  auto issue = [&](int st) {
#pragma unroll
    for (int it = 0; it < 4; ++it) {
      int task = t + it * 256, r = task >> 3, c = task & 7, gr = rowbase + r;
      pa[it] = hz;
      if (gr < NPTS) pa[it] = *(const s16x8*)(xb + (size_t)gr * INC + st * 64 + c * 8);
      pb[it] = hz;
      if (task < 832)
        pb[it] = *(const s16x8*)(w1t + (size_t)(cb * WID + r) * INC + st * 64 + c * 8);
    }
  };
  auto writeT = [&]() {
#pragma unroll
    for (int it = 0; it < 4; ++it) {
      int task = t + it * 256, r = task >> 3, c = task & 7;
      *(s16x8*)(Al + ((r * 128 + c * 16) ^ ((r & 7) << 4))) = pa[it];
      if (task < 896) *(s16x8*)(Bl + ((r * 128 + c * 16) ^ ((r & 7) << 4))) = pb[it];
    }
  };
  auto compute = [&]() {
#pragma unroll
    for (int kc = 0; kc < 2; ++kc) {
      int co = kc * 64 + lg * 16;
      s16x8 a[2], b[7];
#pragma unroll
      for (int mt = 0; mt < 2; ++mt) {
        int r = wv * 32 + mt * 16 + lr;
        a[mt] = *(const s16x8*)(Al + ((r * 128 + co) ^ ((r & 7) << 4)));
      }
#pragma unroll
      for (int ct = 0; ct < 7; ++ct) {
        int r = ct * 16 + lr;
        b[ct] = *(const s16x8*)(Bl + ((r * 128 + co) ^ ((r & 7) << 4)));
      }
#pragma unroll
      for (int mt = 0; mt < 2; ++mt)
#pragma unroll
        for (int ct = 0; ct < 7; ++ct) mfma16(acc[mt][ct], a[mt], b[ct]);
    }
  };

  issue(0);
  for (int st = 0; st < 4; ++st) {
    writeT();
    __syncthreads();
    if (st < 3) issue(st + 1);
    compute();
    if (st < 3) rawbar();
  }
  __syncthreads();
  float* S = (float*)Al;
#pragma unroll
  for (int ct = 0; ct < 7; ++ct) {
    float s = 0.f, q = 0.f;
#pragma unroll
    for (int mt = 0; mt < 2; ++mt)
#pragma unroll
      for (int j = 0; j < 4; ++j) { float v = acc[mt][ct][j]; s += v; q += v * v; }
    s += __shfl_xor(s, 16); s += __shfl_xor(s, 32);
    q += __shfl_xor(q, 16); q += __shfl_xor(q, 32);
    if (lane < 16) {
      S[wv * 224 + ct * 16 + lane] = s;
      S[wv * 224 + 112 + ct * 16 + lane] = q;
    }
  }
  __syncthreads();
  if (t < 224) {
    float v = S[t] + S[224 + t] + S[448 + t] + S[672 + t];
    int cl = (t < 112) ? t : t - 112;
    if (cl < WID) {
      float* base = stats + (blockIdx.x & 7) * 832;
      atomicAdd(base + ((t < 112) ? 0 : WSC) + cb * WID + cl, v);
    }
  }
  __syncthreads();
#pragma unroll
  for (int mt = 0; mt < 2; ++mt)
#pragma unroll
    for (int ct = 0; ct < 7; ++ct)
#pragma unroll
      for (int j = 0; j < 4; ++j) {
        int r = rowbase + wv * 32 + mt * 16 + lg * 4 + j;
        int cl = ct * 16 + lr;
        if (r < NPTS && cl < WID)
          y1[(size_t)r * WSC + cb * WID + cl] = f2bf(acc[mt][ct][j]);
      }
}

// ---------------- sparse conv: barrier-free, A gathered direct to frags ----------------
__global__ __launch_bounds__(256, 3) void k_conv(const u16* __restrict__ src,
    const int* __restrict__ nbr, const u16* __restrict__ wcf,
    u16* __restrict__ z, float* __restrict__ stats) {
  __shared__ float S[896];
  const int t = threadIdx.x, rowbase = blockIdx.x * 128;
  const int lane = t & 63, wv = t >> 6, lr = lane & 15, lg = lane >> 4;
  const int ch = lg * 8;
  const f32x4 fz = {0.f, 0.f, 0.f, 0.f};
  f32x4 acc[2][7];
#pragma unroll
  for (int i = 0; i < 2; ++i)
#pragma unroll
    for (int j = 0; j < 7; ++j) acc[i][j] = fz;

  const int rm0 = rowbase + wv * 32 + lr;
  const int rm1 = rm0 + 16;
  const bool ok0 = rm0 < NPTS, ok1 = rm1 < NPTS;
  const int* np0 = nbr + (size_t)(ok0 ? rm0 : 0) * KOFF;
  const int* np1 = nbr + (size_t)(ok1 ? rm1 : 0) * KOFF;
  const u16* bp = wcf + (size_t)lane * 8;

  s16x8 aC0, aC1, aN0, aN1;
  s16x8 bf[7];
  int ic0, ic1, in0, in1;

  auto GA = [&](int i0, int i1, int kc, s16x8& d0, s16x8& d1) {
    d0 = *(const s16x8*)(src + (size_t)i0 * SPAD + kc * 32 + ch);
    d1 = *(const s16x8*)(src + (size_t)i1 * SPAD + kc * 32 + ch);
  };
  auto LB = [&](int k, int kc) {
#pragma unroll
    for (int ct = 0; ct < 7; ++ct)
      bf[ct] = *(const s16x8*)(bp + (size_t)(k * 28 + ct * 4 + kc) * 512);
  };
  auto MM = [&](s16x8& a0, s16x8& a1) {
#pragma unroll
    for (int ct = 0; ct < 7; ++ct) {
      mfma16(acc[0][ct], a0, bf[ct]);
      mfma16(acc[1][ct], a1, bf[ct]);
    }
  };

  ic0 = ok0 ? np0[0] : NPTS;
  ic1 = ok1 ? np1[0] : NPTS;
  GA(ic0, ic1, 0, aC0, aC1);
  in0 = ok0 ? np0[1] : NPTS;
  in1 = ok1 ? np1[1] : NPTS;

  for (int k = 0; k < KOFF; ++k) {
    LB(k, 0); GA(ic0, ic1, 1, aN0, aN1); MM(aC0, aC1);
    LB(k, 1); GA(ic0, ic1, 2, aC0, aC1); MM(aN0, aN1);
    LB(k, 2); GA(ic0, ic1, 3, aN0, aN1); MM(aC0, aC1);
    LB(k, 3);
    if (k < KOFF - 1) GA(in0, in1, 0, aC0, aC1);
    MM(aN0, aN1);
    int t0 = NPTS, t1 = NPTS;
    if (k < KOFF - 2) {
      t0 = ok0 ? np0[k + 2] : NPTS;
      t1 = ok1 ? np1[k + 2] : NPTS;
    }
    ic0 = in0; ic1 = in1; in0 = t0; in1 = t1;
  }

  // block stats reduce + banked atomics
  __syncthreads();
#pragma unroll
  for (int ct = 0; ct < 7; ++ct) {
    float s = 0.f, q = 0.f;
#pragma unroll
    for (int mt = 0; mt < 2; ++mt)
#pragma unroll
      for (int j = 0; j < 4; ++j) { float v = acc[mt][ct][j]; s += v; q += v * v; }
    s += __shfl_xor(s, 16); s += __shfl_xor(s, 32);
    q += __shfl_xor(q, 16); q += __shfl_xor(q, 32);
    if (lane < 16) {
      S[wv * 224 + ct * 16 + lane] = s;
      S[wv * 224 + 112 + ct * 16 + lane] = q;
    }
  }
  __syncthreads();
  if (t < 224) {
    float v = S[t] + S[224 + t] + S[448 + t] + S[672 + t];
    int cl = (t < 112) ? t : t - 112;
    if (cl < WID) {
      float* base = stats + (blockIdx.x & 7) * 208;
      atomicAdd(base + ((t < 112) ? 0 : WID) + cl, v);
    }
  }
#pragma unroll
  for (int mt = 0; mt < 2; ++mt)
#pragma unroll
    for (int ct = 0; ct < 7; ++ct)
#pragma unroll
      for (int j = 0; j < 4; ++j) {
        int r = rowbase + wv * 32 + mt * 16 + lg * 4 + j;
        int cl = ct * 16 + lr;
        if (r < NPTS && cl < WID)
          z[(size_t)r * WID + cl] = f2bf(acc[mt][ct][j]);
      }
}

// ---------------- GEMM3: BN'd cat[N,416] @ W3 -> out[N,256] fp32 + banked stats ----------------
__global__ __launch_bounds__(256) void k_gemm3(const u16* __restrict__ z0,
    const u16* __restrict__ z1, const u16* __restrict__ z2, const u16* __restrict__ y1,
    const u16* __restrict__ w3t, const float* __restrict__ ST, float* __restrict__ out,
    float* __restrict__ st3) {
  __shared__ char Al[128 * 128];
  __shared__ char Bl[128 * 128];
  __shared__ float sscl[416], ssft[416];
  const int t = threadIdx.x, rowbase = blockIdx.x * 128, cb = blockIdx.y;
  const int lane = t & 63, wv = t >> 6, lr = lane & 15, lg = lane >> 4;
  const int wr = wv >> 1, wc = wv & 1;
  const f32x4 fz = {0.f, 0.f, 0.f, 0.f};
  const s16x8 hz = {0, 0, 0, 0, 0, 0, 0, 0};
  for (int i = t; i < 416; i += 256) {
    float sc, sh;
    if (i < 312) {
      int p = i / 104, c = i - p * 104;
      const float* S = ST + STC0_OFF + p * 1872;
      sc = S[1664 + c]; sh = S[1768 + c];
    } else { sc = ST[6656 + i]; sh = ST[7072 + i]; }
    sscl[i] = sc; ssft[i] = sh;
  }
  f32x4 acc[4][4];
#pragma unroll
  for (int i = 0; i < 4; ++i)
#pragma unroll
    for (int j = 0; j < 4; ++j) acc[i][j] = fz;
  s16x8 pa[4], pb[4];

  auto issue = [&](int st) {
#pragma unroll
    for (int it = 0; it < 4; ++it) {
      int task = t + it * 256, r = task >> 3, c = task & 7;
      int gr = rowbase + r, gc = st * 8 + c;
      pa[it] = hz;
      if (gr < NPTS && gc < 52) {
        int p = gc / 13, cc8 = (gc - p * 13) * 8;
        const u16* s = (p == 0) ? z0 + (size_t)gr * WID + cc8
                     : (p == 1) ? z1 + (size_t)gr * WID + cc8
                     : (p == 2) ? z2 + (size_t)gr * WID + cc8
                                : y1 + (size_t)gr * WSC + 312 + cc8;
        pa[it] = *(const s16x8*)s;
      }
      int gk = st * 64 + c * 8;
      pb[it] = hz;
      if (gk < WSC) pb[it] = *(const s16x8*)(w3t + (size_t)(cb * 128 + r) * WSC + gk);
    }
  };
  auto writeT = [&](int st) {
#pragma unroll
    for (int it = 0; it < 4; ++it) {
      int task = t + it * 256, r = task >> 3, c = task & 7;
      int gr = rowbase + r, gc = st * 8 + c;
      s16x8 h = hz;
      if (gr < NPTS && gc < 52) {
        int p = gc / 13;
        int colb = p * WID + (gc - p * 13) * 8;
#pragma unroll
        for (int j = 0; j < 8; ++j) {
          float f = fmaxf(bf2f((u16)pa[it][j]) * sscl[colb + j] + ssft[colb + j], 0.f);
          h[j] = (short)f2bf(f);
        }
      }
      *(s16x8*)(Al + ((r * 128 + c * 16) ^ ((r & 7) << 4))) = h;
      *(s16x8*)(Bl + ((r * 128 + c * 16) ^ ((r & 7) << 4))) = pb[it];
    }
  };
  auto compute = [&]() {
#pragma unroll
    for (int kc = 0; kc < 2; ++kc) {
      int co = kc * 64 + lg * 16;
      s16x8 a[4], b[4];
#pragma unroll
      for (int mt = 0; mt < 4; ++mt) {
        int r = wr * 64 + mt * 16 + lr;
        a[mt] = *(const s16x8*)(Al + ((r * 128 + co) ^ ((r & 7) << 4)));
      }
#pragma unroll
      for (int ct = 0; ct < 4; ++ct) {
        int r = wc * 64 + ct * 16 + lr;
        b[ct] = *(const s16x8*)(Bl + ((r * 128 + co) ^ ((r & 7) << 4)));
      }
#pragma unroll
      for (int mt = 0; mt < 4; ++mt)
#pragma unroll
        for (int ct = 0; ct < 4; ++ct) mfma16(acc[mt][ct], a[mt], b[ct]);
    }
  };

  issue(0);
  __syncthreads();
  for (int st = 0; st < 7; ++st) {
    writeT(st);
    __syncthreads();
    if (st < 6) issue(st + 1);
    compute();
    if (st < 6) rawbar();
  }
  __syncthreads();
  float* S = (float*)Al;
#pragma unroll
  for (int ct = 0; ct < 4; ++ct) {
    float s = 0.f, q = 0.f;
#pragma unroll
    for (int mt = 0; mt < 4; ++mt)
#pragma unroll
      for (int j = 0; j < 4; ++j) { float v = acc[mt][ct][j]; s += v; q += v * v; }
    s += __shfl_xor(s, 16); s += __shfl_xor(s, 32);
    q += __shfl_xor(q, 16); q += __shfl_xor(q, 32);
    if (lane < 16) {
      S[wv * 128 + ct * 16 + lane] = s;
      S[wv * 128 + 64 + ct * 16 + lane] = q;
    }
  }
  __syncthreads();
  {
    float* base = st3 + (blockIdx.x & 7) * 512;
    if (t < 64) atomicAdd(base + cb * 128 + t, S[t] + S[256 + t]);
    else if (t < 128) atomicAdd(base + INC + cb * 128 + (t - 64), S[64 + t - 64] + S[320 + t - 64]);
    else if (t < 192) atomicAdd(base + cb * 128 + 64 + (t - 128), S[128 + t - 128] + S[384 + t - 128]);
    else atomicAdd(base + INC + cb * 128 + 64 + (t - 192), S[192 + t - 192] + S[448 + t - 192]);
  }
#pragma unroll
  for (int mt = 0; mt < 4; ++mt)
#pragma unroll
    for (int ct = 0; ct < 4; ++ct)
#pragma unroll
      for (int j = 0; j < 4; ++j) {
        int r = rowbase + wr * 64 + mt * 16 + lg * 4 + j;
        int col = cb * 128 + wc * 64 + ct * 16 + lr;
        if (r < NPTS) out[(size_t)r * INC + col] = acc[mt][ct][j];
      }
}

// ---------------- stats finalize: sum 8 banks -> scale/shift ----------------
__global__ __launch_bounds__(512) void k_finstats(float* st, const float* __restrict__ g,
                                                  const float* __restrict__ b, int C) {
  int c = threadIdx.x;
  if (c < C) {
    float s = 0.f, q = 0.f;
#pragma unroll
    for (int bk = 0; bk < 8; ++bk) { s += st[bk * 2 * C + c]; q += st[bk * 2 * C + C + c]; }
    float m = s * (1.f / NPTS);
    float var = q * (1.f / NPTS) - m * m;
    float rs = rsqrtf(var + EPSV);
    float sc = rs * g[c];
    st[16 * C + c] = sc;
    st[17 * C + c] = b[c] - m * sc;
  }
}

// ---------------- mix: SPXp = [relu(bnc(Z)) +] relu(bn1(Y1 slice)), padded rows ----------------
template <int HASZ>
__global__ __launch_bounds__(256) void k_mix(const u16* __restrict__ y1, int yoff,
    const float* __restrict__ scl1, const float* __restrict__ sft1,
    const u16* __restrict__ z, const float* __restrict__ sclc, const float* __restrict__ sftc,
    u16* __restrict__ spx) {
  const int total = NPTS * 13;
  for (int i = blockIdx.x * 256 + threadIdx.x; i < total; i += gridDim.x * 256) {
    int r = i / 13, cc = i - r * 13;
    s16x8 y = *(const s16x8*)(y1 + (size_t)r * WSC + yoff + cc * 8);
    s16x8 zv;
    if (HASZ) zv = *(const s16x8*)(z + (size_t)r * WID + cc * 8);
    s16x8 o;
#pragma unroll
    for (int j = 0; j < 8; ++j) {
      int c = cc * 8 + j;
      float f = fmaxf(bf2f((u16)y[j]) * scl1[c] + sft1[c], 0.f);
      if (HASZ) f += fmaxf(bf2f((u16)zv[j]) * sclc[c] + sftc[c], 0.f);
      o[j] = (short)f2bf(f);
    }
    *(s16x8*)(spx + (size_t)r * SPAD + cc * 8) = o;
  }
}

// ---------------- final: out = relu(out*sc + sh + x) ----------------
__global__ __launch_bounds__(256) void k_final(float* __restrict__ y,
    const float* __restrict__ scale, const float* __restrict__ shift,
    const float* __restrict__ x) {
  const int total = NPTS * 64;
  for (int i = blockIdx.x * 256 + threadIdx.x; i < total; i += gridDim.x * 256) {
    int r = i >> 6, cc = i & 63;
    f32x4 v = *(f32x4*)(y + (size_t)r * INC + cc * 4);
    f32x4 xf = *(const f32x4*)(x + (size_t)r * INC + cc * 4);
#pragma unroll
    for (int j = 0; j < 4; ++j) {
      int c = cc * 4 + j;
      v[j] = fmaxf(v[j] * scale[c] + shift[c] + xf[j], 0.f);
    }
    *(f32x4*)(y + (size_t)r * INC + cc * 4) = v;
  }
}

// ---------------- launch ----------------
extern "C" void kernel_launch(void* const* d_in, const int* in_sizes, int n_in,
                              void* d_out, int out_size, void* d_ws, size_t ws_size,
                              hipStream_t stream) {
  const float* x  = (const float*)d_in[0];
  const int* nbr  = (const int*)d_in[1];
  const float* W1 = (const float*)d_in[2];
  const float* g1 = (const float*)d_in[3];
  const float* b1 = (const float*)d_in[4];
  const float* Wc = (const float*)d_in[5];
  const float* gc = (const float*)d_in[6];
  const float* bc = (const float*)d_in[7];
  const float* W3 = (const float*)d_in[8];
  const float* g3 = (const float*)d_in[9];
  const float* b3 = (const float*)d_in[10];
  float* out = (float*)d_out;

  char* ws = (char*)d_ws;
  size_t off = 0;
  auto alloc = [&](size_t n) {
    char* p = ws + off;
    off += (n + 255) & ~(size_t)255;
    return p;
  };
  u16* W1T = (u16*)alloc(416 * 256 * 2);
  u16* W3T = (u16*)alloc(256 * 416 * 2);
  u16* WCF = (u16*)alloc((size_t)3 * 27 * 28 * 512 * 2);
  u16* XB  = (u16*)alloc((size_t)NPTS * INC * 2);
  u16* Y1  = (u16*)alloc((size_t)NPTS * WSC * 2);
  u16* Z0  = (u16*)alloc((size_t)NPTS * WID * 2);
  u16* Z1  = (u16*)alloc((size_t)NPTS * WID * 2);
  u16* Z2  = (u16*)alloc((size_t)NPTS * WID * 2);
  u16* SPX = (u16*)alloc((size_t)(NPTS + 1) * SPAD * 2);
  float* ST = (float*)alloc(ST_TOTAL * 4);
  float* ST1  = ST + ST1_OFF;
  float* STC0 = ST + STC0_OFF;
  float* STC1 = ST + STC1_OFF;
  float* STC2 = ST + STC2_OFF;
  float* ST3  = ST + ST3_OFF;

  k_prep_w1w3<<<832, 256, 0, stream>>>(W1, W3, W1T, W3T);
  k_prep_wc<<<81, 256, 0, stream>>>(Wc, WCF);
  k_init<<<256, 256, 0, stream>>>(ST, SPX);
  k_xbf<<<2048, 256, 0, stream>>>(x, XB);

  k_gemm1<<<dim3(782, 4), 256, 0, stream>>>(XB, W1T, Y1, ST1);
  k_finstats<<<1, 512, 0, stream>>>(ST1, g1, b1, WSC);

  const size_t WCL = (size_t)27 * 28 * 512;
  // branch 0
  k_mix<0><<<2048, 256, 0, stream>>>(Y1, 0, ST1 + 6656, ST1 + 7072, nullptr, nullptr, nullptr, SPX);
  k_conv<<<782, 256, 0, stream>>>(SPX, nbr, WCF, Z0, STC0);
  k_finstats<<<1, 512, 0, stream>>>(STC0, gc, bc, WID);
  // branch 1
  k_mix<1><<<2048, 256, 0, stream>>>(Y1, 104, ST1 + 6656 + 104, ST1 + 7072 + 104,
                                     Z0, STC0 + 1664, STC0 + 1768, SPX);
  k_conv<<<782, 256, 0, stream>>>(SPX, nbr, WCF + WCL, Z1, STC1);
  k_finstats<<<1, 512, 0, stream>>>(STC1, gc + 104, bc + 104, WID);
  // branch 2
  k_mix<1><<<2048, 256, 0, stream>>>(Y1, 208, ST1 + 6656 + 208, ST1 + 7072 + 208,
                                     Z1, STC1 + 1664, STC1 + 1768, SPX);
  k_conv<<<782, 256, 0, stream>>>(SPX, nbr, WCF + 2 * WCL, Z2, STC2);
  k_finstats<<<1, 512, 0, stream>>>(STC2, gc + 208, bc + 208, WID);

  k_gemm3<<<dim3(782, 2), 256, 0, stream>>>(Z0, Z1, Z2, Y1, W3T, ST, out, ST3);
  k_finstats<<<1, 512, 0, stream>>>(ST3, g3, b3, INC);
  k_final<<<2048, 256, 0, stream>>>(out, ST3 + 4096, ST3 + 4352, x);
}

// Round 5
// 723.745 us; speedup vs baseline: 1.7984x; 1.7984x over previous
//
#include <hip/hip_runtime.h>

#define NPTS 100000
#define INC 256
#define WID 104
#define WSC 416
#define KOFF 27
#define EPSV 1e-5f

typedef unsigned short u16;
typedef float f32x4 __attribute__((ext_vector_type(4)));
typedef short s16x8 __attribute__((ext_vector_type(8)));

__device__ __forceinline__ u16 f2bf(float f) {
  unsigned u = __builtin_bit_cast(unsigned, f);
  u += 0x7FFFu + ((u >> 16) & 1u);
  return (u16)(u >> 16);
}
__device__ __forceinline__ float bf2f(u16 h) {
  unsigned u = ((unsigned)h) << 16;
  return __builtin_bit_cast(float, u);
}
__device__ __forceinline__ void mfma16(f32x4& d, s16x8 a, s16x8 b) {
  asm("v_mfma_f32_16x16x32_bf16 %0, %1, %2, %0" : "+v"(d) : "v"(a), "v"(b));
}
__device__ __forceinline__ void rawbar() {
  __builtin_amdgcn_s_barrier();
  __builtin_amdgcn_sched_barrier(0);
}

// stats region layout (floats): [8 banks][sum C][sumsq C], then [scale C][shift C]
#define ST1_OFF 0
#define STC0_OFF 7488
#define STC1_OFF 9360
#define STC2_OFF 11232
#define ST3_OFF 13104
#define ST_TOTAL 17712

// SPX padded row stride (elems) -> 256B-aligned rows, exactly 2 cache lines each
#define SPAD 128

// ---------------- weight prep ----------------
__global__ __launch_bounds__(256) void k_prep_w1w3(const float* __restrict__ w1,
    const float* __restrict__ w3, u16* __restrict__ w1t, u16* __restrict__ w3t) {
  int i = blockIdx.x * 256 + threadIdx.x;
  if (i < 416 * 256) {
    int n = i >> 8, k = i & 255;
    w1t[i] = f2bf(w1[(size_t)k * WSC + n]);
  } else if (i < 2 * 416 * 256) {
    int o = i - 416 * 256;
    int n = o / WSC, k = o - n * WSC;
    w3t[o] = f2bf(w3[(size_t)k * INC + n]);
  }
}

// WCT layout: [branch*27+k][112 rows=out-col (8 pad)][104 cols=k-in] bf16
__global__ __launch_bounds__(256) void k_prep_wc(const float* __restrict__ wc,
                                                 u16* __restrict__ wct) {
  __shared__ float w[WID * WID];
  int b = blockIdx.x, t = threadIdx.x;
  const float* s = wc + (size_t)b * WID * WID;
  for (int i = t; i < WID * WID; i += 256) w[i] = s[i];
  __syncthreads();
  u16* d = wct + (size_t)b * 112 * WID;
  for (int o = t; o < 112 * WID; o += 256) {
    int n = o / WID, kin = o - n * WID;
    d[o] = f2bf((n < WID) ? w[kin * WID + n] : 0.f);
  }
}

__global__ void k_init(float* __restrict__ st, u16* __restrict__ spxp) {
  const s16x8 hz = {0, 0, 0, 0, 0, 0, 0, 0};
  int i = blockIdx.x * 256 + threadIdx.x;
  if (i < ST_TOTAL) st[i] = 0.f;
  // zero pad chunks 13..15 of every row (incl. row NPTS)
  for (int task = i; task < (NPTS + 1) * 3; task += gridDim.x * 256) {
    int r = task / 3, c = task - 3 * r;
    *(s16x8*)(spxp + (size_t)r * SPAD + (13 + c) * 8) = hz;
  }
  // zero data chunks of row NPTS
  if (blockIdx.x == 0 && threadIdx.x < 13)
    *(s16x8*)(spxp + (size_t)NPTS * SPAD + threadIdx.x * 8) = hz;
}

// ---------------- x -> bf16 ----------------
__global__ __launch_bounds__(256) void k_xbf(const float* __restrict__ x,
                                             u16* __restrict__ xb) {
  const int total = NPTS * INC / 8;
  for (int i = blockIdx.x * 256 + threadIdx.x; i < total; i += gridDim.x * 256) {
    const f32x4* s = (const f32x4*)(x + (size_t)i * 8);
    f32x4 v0 = s[0], v1 = s[1];
    s16x8 h;
#pragma unroll
    for (int j = 0; j < 4; ++j) { h[j] = (short)f2bf(v0[j]); h[4 + j] = (short)f2bf(v1[j]); }
    *(s16x8*)(xb + (size_t)i * 8) = h;
  }
}

// ---------------- GEMM1: xb[N,256] @ W1 -> Y1[N,416] bf16 raw + banked col stats ----------------
__global__ __launch_bounds__(256) void k_gemm1(const u16* __restrict__ xb,
    const u16* __restrict__ w1t, u16* __restrict__ y1, float* __restrict__ stats) {
  __shared__ char Al[128 * 128];
  __shared__ char Bl[112 * 128];
  const int t = threadIdx.x, rowbase = blockIdx.x * 128, cb = blockIdx.y;
  const int lane = t & 63, wv = t >> 6, lr = lane & 15, lg = lane >> 4;
  const f32x4 fz = {0.f, 0.f, 0.f, 0.f};
  const s16x8 hz = {0, 0, 0, 0, 0, 0, 0, 0};
  f32x4 acc[2][7];
#pragma unroll
  for (int i = 0; i < 2; ++i)
#pragma unroll
    for (int j = 0; j < 7; ++j) acc[i][j] = fz;
  s16x8 pa[4], pb[4];

  auto issue = [&](int st) {
#pragma unroll
    for (int it = 0; it < 4; ++it) {
      int task = t + it * 256, r = task >> 3, c = task & 7, gr = rowbase + r;
      pa[it] = hz;
      if (gr < NPTS) pa[it] = *(const s16x8*)(xb + (size_t)gr * INC + st * 64 + c * 8);
      pb[it] = hz;
      if (task < 832)
        pb[it] = *(const s16x8*)(w1t + (size_t)(cb * WID + r) * INC + st * 64 + c * 8);
    }
  };
  auto writeT = [&]() {
#pragma unroll
    for (int it = 0; it < 4; ++it) {
      int task = t + it * 256, r = task >> 3, c = task & 7;
      *(s16x8*)(Al + ((r * 128 + c * 16) ^ ((r & 7) << 4))) = pa[it];
      if (task < 896) *(s16x8*)(Bl + ((r * 128 + c * 16) ^ ((r & 7) << 4))) = pb[it];
    }
  };
  auto compute = [&]() {
#pragma unroll
    for (int kc = 0; kc < 2; ++kc) {
      int co = kc * 64 + lg * 16;
      s16x8 a[2], b[7];
#pragma unroll
      for (int mt = 0; mt < 2; ++mt) {
        int r = wv * 32 + mt * 16 + lr;
        a[mt] = *(const s16x8*)(Al + ((r * 128 + co) ^ ((r & 7) << 4)));
      }
#pragma unroll
      for (int ct = 0; ct < 7; ++ct) {
        int r = ct * 16 + lr;
        b[ct] = *(const s16x8*)(Bl + ((r * 128 + co) ^ ((r & 7) << 4)));
      }
#pragma unroll
      for (int mt = 0; mt < 2; ++mt)
#pragma unroll
        for (int ct = 0; ct < 7; ++ct) mfma16(acc[mt][ct], a[mt], b[ct]);
    }
  };

  issue(0);
  for (int st = 0; st < 4; ++st) {
    writeT();
    __syncthreads();
    if (st < 3) issue(st + 1);
    compute();
    if (st < 3) rawbar();
  }
  __syncthreads();
  float* S = (float*)Al;
#pragma unroll
  for (int ct = 0; ct < 7; ++ct) {
    float s = 0.f, q = 0.f;
#pragma unroll
    for (int mt = 0; mt < 2; ++mt)
#pragma unroll
      for (int j = 0; j < 4; ++j) { float v = acc[mt][ct][j]; s += v; q += v * v; }
    s += __shfl_xor(s, 16); s += __shfl_xor(s, 32);
    q += __shfl_xor(q, 16); q += __shfl_xor(q, 32);
    if (lane < 16) {
      S[wv * 224 + ct * 16 + lane] = s;
      S[wv * 224 + 112 + ct * 16 + lane] = q;
    }
  }
  __syncthreads();
  if (t < 224) {
    float v = S[t] + S[224 + t] + S[448 + t] + S[672 + t];
    int cl = (t < 112) ? t : t - 112;
    if (cl < WID) {
      float* base = stats + (blockIdx.x & 7) * 832;
      atomicAdd(base + ((t < 112) ? 0 : WSC) + cb * WID + cl, v);
    }
  }
  __syncthreads();
#pragma unroll
  for (int mt = 0; mt < 2; ++mt)
#pragma unroll
    for (int ct = 0; ct < 7; ++ct)
#pragma unroll
      for (int j = 0; j < 4; ++j) {
        int r = rowbase + wv * 32 + mt * 16 + lg * 4 + j;
        int cl = ct * 16 + lr;
        if (r < NPTS && cl < WID)
          y1[(size_t)r * WSC + cb * WID + cl] = f2bf(acc[mt][ct][j]);
      }
}

// ---------------- sparse conv: LDS-staged burst gather (R3 structure, aligned source) ----------------
__global__ __launch_bounds__(256) void k_conv(const u16* __restrict__ src,
    const int* __restrict__ nbr, const u16* __restrict__ wct,
    u16* __restrict__ z, float* __restrict__ stats) {
  __shared__ char Al[128 * 208];   // 128 rows x 104 bf16, stride 208B (2-way banks = free)
  __shared__ char Bl[112 * 208];
  const int t = threadIdx.x, rowbase = blockIdx.x * 128;
  const int lane = t & 63, wv = t >> 6, lr = lane & 15, lg = lane >> 4;
  const f32x4 fz = {0.f, 0.f, 0.f, 0.f};
  const s16x8 hz = {0, 0, 0, 0, 0, 0, 0, 0};
  f32x4 acc[2][7];
#pragma unroll
  for (int i = 0; i < 2; ++i)
#pragma unroll
    for (int j = 0; j < 7; ++j) acc[i][j] = fz;
  s16x8 pa[8], pb[6];
  int pidx[8];

  auto idxIssue = [&](int kk) {
#pragma unroll
    for (int it = 0; it < 8; ++it) {
      int r = (t + it * 256) >> 4, gr = rowbase + r;
      pidx[it] = (gr < NPTS) ? nbr[gr * KOFF + kk] : NPTS;
    }
  };
  auto gatherIssue = [&]() {
#pragma unroll
    for (int it = 0; it < 8; ++it) {
      int c = (t + it * 256) & 15;
      pa[it] = hz;
      if (c < 13)
        pa[it] = *(const s16x8*)(src + (size_t)pidx[it] * SPAD + c * 8);
    }
  };
  auto loadB = [&](int k) {
#pragma unroll
    for (int it = 0; it < 6; ++it) {
      int task = t + it * 256;
      if (task < 1456) {
        int r = task / 13, c = task - 13 * r;
        pb[it] = *(const s16x8*)(wct + ((size_t)k * 112 + r) * WID + c * 8);
      }
    }
  };
  auto writeA = [&]() {
#pragma unroll
    for (int it = 0; it < 8; ++it) {
      int task = t + it * 256, r = task >> 4, c = task & 15;
      if (c < 13) *(s16x8*)(Al + r * 208 + c * 16) = pa[it];
    }
  };
  auto writeB = [&]() {
#pragma unroll
    for (int it = 0; it < 6; ++it) {
      int task = t + it * 256;
      if (task < 1456) {
        int r = task / 13, c = task - 13 * r;
        *(s16x8*)(Bl + r * 208 + c * 16) = pb[it];
      }
    }
  };
  auto compute = [&]() {
#pragma unroll
    for (int kc = 0; kc < 3; ++kc) {
      int co = kc * 64 + lg * 16;
      s16x8 a[2], b[7];
#pragma unroll
      for (int mt = 0; mt < 2; ++mt)
        a[mt] = *(const s16x8*)(Al + (wv * 32 + mt * 16 + lr) * 208 + co);
#pragma unroll
      for (int ct = 0; ct < 7; ++ct)
        b[ct] = *(const s16x8*)(Bl + (ct * 16 + lr) * 208 + co);
#pragma unroll
      for (int mt = 0; mt < 2; ++mt)
#pragma unroll
        for (int ct = 0; ct < 7; ++ct) mfma16(acc[mt][ct], a[mt], b[ct]);
    }
    { // K tail: elements 96..103
      s16x8 a[2], b[7];
#pragma unroll
      for (int mt = 0; mt < 2; ++mt)
        a[mt] = (lg == 0) ? *(const s16x8*)(Al + (wv * 32 + mt * 16 + lr) * 208 + 192) : hz;
#pragma unroll
      for (int ct = 0; ct < 7; ++ct)
        b[ct] = (lg == 0) ? *(const s16x8*)(Bl + (ct * 16 + lr) * 208 + 192) : hz;
#pragma unroll
      for (int mt = 0; mt < 2; ++mt)
#pragma unroll
        for (int ct = 0; ct < 7; ++ct) mfma16(acc[mt][ct], a[mt], b[ct]);
    }
  };

  idxIssue(0);
  gatherIssue();
  loadB(0);
  idxIssue(1);
  for (int k = 0; k < KOFF; ++k) {
    writeA();
    writeB();
    __syncthreads();
    if (k < KOFF - 1) {
      gatherIssue();
      loadB(k + 1);
      if (k < KOFF - 2) idxIssue(k + 2);
    }
    compute();
    if (k < KOFF - 1) rawbar();
  }
  // block stats reduce + banked atomics
  __syncthreads();
  float* S = (float*)Al;
#pragma unroll
  for (int ct = 0; ct < 7; ++ct) {
    float s = 0.f, q = 0.f;
#pragma unroll
    for (int mt = 0; mt < 2; ++mt)
#pragma unroll
      for (int j = 0; j < 4; ++j) { float v = acc[mt][ct][j]; s += v; q += v * v; }
    s += __shfl_xor(s, 16); s += __shfl_xor(s, 32);
    q += __shfl_xor(q, 16); q += __shfl_xor(q, 32);
    if (lane < 16) {
      S[wv * 224 + ct * 16 + lane] = s;
      S[wv * 224 + 112 + ct * 16 + lane] = q;
    }
  }
  __syncthreads();
  if (t < 224) {
    float v = S[t] + S[224 + t] + S[448 + t] + S[672 + t];
    int cl = (t < 112) ? t : t - 112;
    if (cl < WID) {
      float* base = stats + (blockIdx.x & 7) * 208;
      atomicAdd(base + ((t < 112) ? 0 : WID) + cl, v);
    }
  }
  __syncthreads();
#pragma unroll
  for (int mt = 0; mt < 2; ++mt)
#pragma unroll
    for (int ct = 0; ct < 7; ++ct)
#pragma unroll
      for (int j = 0; j < 4; ++j) {
        int r = rowbase + wv * 32 + mt * 16 + lg * 4 + j;
        int cl = ct * 16 + lr;
        if (r < NPTS && cl < WID)
          z[(size_t)r * WID + cl] = f2bf(acc[mt][ct][j]);
      }
}

// ---------------- GEMM3: BN'd cat[N,416] @ W3 -> out[N,256] fp32 + banked stats ----------------
__global__ __launch_bounds__(256) void k_gemm3(const u16* __restrict__ z0,
    const u16* __restrict__ z1, const u16* __restrict__ z2, const u16* __restrict__ y1,
    const u16* __restrict__ w3t, const float* __restrict__ ST, float* __restrict__ out,
    float* __restrict__ st3) {
  __shared__ char Al[128 * 128];
  __shared__ char Bl[128 * 128];
  __shared__ float sscl[416], ssft[416];
  const int t = threadIdx.x, rowbase = blockIdx.x * 128, cb = blockIdx.y;
  const int lane = t & 63, wv = t >> 6, lr = lane & 15, lg = lane >> 4;
  const int wr = wv >> 1, wc = wv & 1;
  const f32x4 fz = {0.f, 0.f, 0.f, 0.f};
  const s16x8 hz = {0, 0, 0, 0, 0, 0, 0, 0};
  for (int i = t; i < 416; i += 256) {
    float sc, sh;
    if (i < 312) {
      int p = i / 104, c = i - p * 104;
      const float* S = ST + STC0_OFF + p * 1872;
      sc = S[1664 + c]; sh = S[1768 + c];
    } else { sc = ST[6656 + i]; sh = ST[7072 + i]; }
    sscl[i] = sc; ssft[i] = sh;
  }
  f32x4 acc[4][4];
#pragma unroll
  for (int i = 0; i < 4; ++i)
#pragma unroll
    for (int j = 0; j < 4; ++j) acc[i][j] = fz;
  s16x8 pa[4], pb[4];

  auto issue = [&](int st) {
#pragma unroll
    for (int it = 0; it < 4; ++it) {
      int task = t + it * 256, r = task >> 3, c = task & 7;
      int gr = rowbase + r, gc = st * 8 + c;
      pa[it] = hz;
      if (gr < NPTS && gc < 52) {
        int p = gc / 13, cc8 = (gc - p * 13) * 8;
        const u16* s = (p == 0) ? z0 + (size_t)gr * WID + cc8
                     : (p == 1) ? z1 + (size_t)gr * WID + cc8
                     : (p == 2) ? z2 + (size_t)gr * WID + cc8
                                : y1 + (size_t)gr * WSC + 312 + cc8;
        pa[it] = *(const s16x8*)s;
      }
      int gk = st * 64 + c * 8;
      pb[it] = hz;
      if (gk < WSC) pb[it] = *(const s16x8*)(w3t + (size_t)(cb * 128 + r) * WSC + gk);
    }
  };
  auto writeT = [&](int st) {
#pragma unroll
    for (int it = 0; it < 4; ++it) {
      int task = t + it * 256, r = task >> 3, c = task & 7;
      int gr = rowbase + r, gc = st * 8 + c;
      s16x8 h = hz;
      if (gr < NPTS && gc < 52) {
        int p = gc / 13;
        int colb = p * WID + (gc - p * 13) * 8;
#pragma unroll
        for (int j = 0; j < 8; ++j) {
          float f = fmaxf(bf2f((u16)pa[it][j]) * sscl[colb + j] + ssft[colb + j], 0.f);
          h[j] = (short)f2bf(f);
        }
      }
      *(s16x8*)(Al + ((r * 128 + c * 16) ^ ((r & 7) << 4))) = h;
      *(s16x8*)(Bl + ((r * 128 + c * 16) ^ ((r & 7) << 4))) = pb[it];
    }
  };
  auto compute = [&]() {
#pragma unroll
    for (int kc = 0; kc < 2; ++kc) {
      int co = kc * 64 + lg * 16;
      s16x8 a[4], b[4];
#pragma unroll
      for (int mt = 0; mt < 4; ++mt) {
        int r = wr * 64 + mt * 16 + lr;
        a[mt] = *(const s16x8*)(Al + ((r * 128 + co) ^ ((r & 7) << 4)));
      }
#pragma unroll
      for (int ct = 0; ct < 4; ++ct) {
        int r = wc * 64 + ct * 16 + lr;
        b[ct] = *(const s16x8*)(Bl + ((r * 128 + co) ^ ((r & 7) << 4)));
      }
#pragma unroll
      for (int mt = 0; mt < 4; ++mt)
#pragma unroll
        for (int ct = 0; ct < 4; ++ct) mfma16(acc[mt][ct], a[mt], b[ct]);
    }
  };

  issue(0);
  __syncthreads();
  for (int st = 0; st < 7; ++st) {
    writeT(st);
    __syncthreads();
    if (st < 6) issue(st + 1);
    compute();
    if (st < 6) rawbar();
  }
  __syncthreads();
  float* S = (float*)Al;
#pragma unroll
  for (int ct = 0; ct < 4; ++ct) {
    float s = 0.f, q = 0.f;
#pragma unroll
    for (int mt = 0; mt < 4; ++mt)
#pragma unroll
      for (int j = 0; j < 4; ++j) { float v = acc[mt][ct][j]; s += v; q += v * v; }
    s += __shfl_xor(s, 16); s += __shfl_xor(s, 32);
    q += __shfl_xor(q, 16); q += __shfl_xor(q, 32);
    if (lane < 16) {
      S[wv * 128 + ct * 16 + lane] = s;
      S[wv * 128 + 64 + ct * 16 + lane] = q;
    }
  }
  __syncthreads();
  {
    float* base = st3 + (blockIdx.x & 7) * 512;
    if (t < 64) atomicAdd(base + cb * 128 + t, S[t] + S[256 + t]);
    else if (t < 128) atomicAdd(base + INC + cb * 128 + (t - 64), S[64 + t - 64] + S[320 + t - 64]);
    else if (t < 192) atomicAdd(base + cb * 128 + 64 + (t - 128), S[128 + t - 128] + S[384 + t - 128]);
    else atomicAdd(base + INC + cb * 128 + 64 + (t - 192), S[192 + t - 192] + S[448 + t - 192]);
  }
#pragma unroll
  for (int mt = 0; mt < 4; ++mt)
#pragma unroll
    for (int ct = 0; ct < 4; ++ct)
#pragma unroll
      for (int j = 0; j < 4; ++j) {
        int r = rowbase + wr * 64 + mt * 16 + lg * 4 + j;
        int col = cb * 128 + wc * 64 + ct * 16 + lr;
        if (r < NPTS) out[(size_t)r * INC + col] = acc[mt][ct][j];
      }
}

// ---------------- stats finalize: sum 8 banks -> scale/shift ----------------
__global__ __launch_bounds__(512) void k_finstats(float* st, const float* __restrict__ g,
                                                  const float* __restrict__ b, int C) {
  int c = threadIdx.x;
  if (c < C) {
    float s = 0.f, q = 0.f;
#pragma unroll
    for (int bk = 0; bk < 8; ++bk) { s += st[bk * 2 * C + c]; q += st[bk * 2 * C + C + c]; }
    float m = s * (1.f / NPTS);
    float var = q * (1.f / NPTS) - m * m;
    float rs = rsqrtf(var + EPSV);
    float sc = rs * g[c];
    st[16 * C + c] = sc;
    st[17 * C + c] = b[c] - m * sc;
  }
}

// ---------------- mix: SPXp = [relu(bnc(Z)) +] relu(bn1(Y1 slice)), padded rows ----------------
template <int HASZ>
__global__ __launch_bounds__(256) void k_mix(const u16* __restrict__ y1, int yoff,
    const float* __restrict__ scl1, const float* __restrict__ sft1,
    const u16* __restrict__ z, const float* __restrict__ sclc, const float* __restrict__ sftc,
    u16* __restrict__ spx) {
  const int total = NPTS * 13;
  for (int i = blockIdx.x * 256 + threadIdx.x; i < total; i += gridDim.x * 256) {
    int r = i / 13, cc = i - r * 13;
    s16x8 y = *(const s16x8*)(y1 + (size_t)r * WSC + yoff + cc * 8);
    s16x8 zv;
    if (HASZ) zv = *(const s16x8*)(z + (size_t)r * WID + cc * 8);
    s16x8 o;
#pragma unroll
    for (int j = 0; j < 8; ++j) {
      int c = cc * 8 + j;
      float f = fmaxf(bf2f((u16)y[j]) * scl1[c] + sft1[c], 0.f);
      if (HASZ) f += fmaxf(bf2f((u16)zv[j]) * sclc[c] + sftc[c], 0.f);
      o[j] = (short)f2bf(f);
    }
    *(s16x8*)(spx + (size_t)r * SPAD + cc * 8) = o;
  }
}

// ---------------- final: out = relu(out*sc + sh + x) ----------------
__global__ __launch_bounds__(256) void k_final(float* __restrict__ y,
    const float* __restrict__ scale, const float* __restrict__ shift,
    const float* __restrict__ x) {
  const int total = NPTS * 64;
  for (int i = blockIdx.x * 256 + threadIdx.x; i < total; i += gridDim.x * 256) {
    int r = i >> 6, cc = i & 63;
    f32x4 v = *(f32x4*)(y + (size_t)r * INC + cc * 4);
    f32x4 xf = *(const f32x4*)(x + (size_t)r * INC + cc * 4);
#pragma unroll
    for (int j = 0; j < 4; ++j) {
      int c = cc * 4 + j;
      v[j] = fmaxf(v[j] * scale[c] + shift[c] + xf[j], 0.f);
    }
    *(f32x4*)(y + (size_t)r * INC + cc * 4) = v;
  }
}

// ---------------- launch ----------------
extern "C" void kernel_launch(void* const* d_in, const int* in_sizes, int n_in,
                              void* d_out, int out_size, void* d_ws, size_t ws_size,
                              hipStream_t stream) {
  const float* x  = (const float*)d_in[0];
  const int* nbr  = (const int*)d_in[1];
  const float* W1 = (const float*)d_in[2];
  const float* g1 = (const float*)d_in[3];
  const float* b1 = (const float*)d_in[4];
  const float* Wc = (const float*)d_in[5];
  const float* gc = (const float*)d_in[6];
  const float* bc = (const float*)d_in[7];
  const float* W3 = (const float*)d_in[8];
  const float* g3 = (const float*)d_in[9];
  const float* b3 = (const float*)d_in[10];
  float* out = (float*)d_out;

  char* ws = (char*)d_ws;
  size_t off = 0;
  auto alloc = [&](size_t n) {
    char* p = ws + off;
    off += (n + 255) & ~(size_t)255;
    return p;
  };
  u16* W1T = (u16*)alloc(416 * 256 * 2);
  u16* W3T = (u16*)alloc(256 * 416 * 2);
  u16* WCT = (u16*)alloc((size_t)3 * 27 * 112 * 104 * 2);
  u16* XB  = (u16*)alloc((size_t)NPTS * INC * 2);
  u16* Y1  = (u16*)alloc((size_t)NPTS * WSC * 2);
  u16* Z0  = (u16*)alloc((size_t)NPTS * WID * 2);
  u16* Z1  = (u16*)alloc((size_t)NPTS * WID * 2);
  u16* Z2  = (u16*)alloc((size_t)NPTS * WID * 2);
  u16* SPX = (u16*)alloc((size_t)(NPTS + 1) * SPAD * 2);
  float* ST = (float*)alloc(ST_TOTAL * 4);
  float* ST1  = ST + ST1_OFF;
  float* STC0 = ST + STC0_OFF;
  float* STC1 = ST + STC1_OFF;
  float* STC2 = ST + STC2_OFF;
  float* ST3  = ST + ST3_OFF;

  k_prep_w1w3<<<832, 256, 0, stream>>>(W1, W3, W1T, W3T);
  k_prep_wc<<<81, 256, 0, stream>>>(Wc, WCT);
  k_init<<<256, 256, 0, stream>>>(ST, SPX);
  k_xbf<<<2048, 256, 0, stream>>>(x, XB);

  k_gemm1<<<dim3(782, 4), 256, 0, stream>>>(XB, W1T, Y1, ST1);
  k_finstats<<<1, 512, 0, stream>>>(ST1, g1, b1, WSC);

  const size_t WCL = (size_t)27 * 112 * WID;
  // branch 0
  k_mix<0><<<2048, 256, 0, stream>>>(Y1, 0, ST1 + 6656, ST1 + 7072, nullptr, nullptr, nullptr, SPX);
  k_conv<<<782, 256, 0, stream>>>(SPX, nbr, WCT, Z0, STC0);
  k_finstats<<<1, 512, 0, stream>>>(STC0, gc, bc, WID);
  // branch 1
  k_mix<1><<<2048, 256, 0, stream>>>(Y1, 104, ST1 + 6656 + 104, ST1 + 7072 + 104,
                                     Z0, STC0 + 1664, STC0 + 1768, SPX);
  k_conv<<<782, 256, 0, stream>>>(SPX, nbr, WCT + WCL, Z1, STC1);
  k_finstats<<<1, 512, 0, stream>>>(STC1, gc + 104, bc + 104, WID);
  // branch 2
  k_mix<1><<<2048, 256, 0, stream>>>(Y1, 208, ST1 + 6656 + 208, ST1 + 7072 + 208,
                                     Z1, STC1 + 1664, STC1 + 1768, SPX);
  k_conv<<<782, 256, 0, stream>>>(SPX, nbr, WCT + 2 * WCL, Z2, STC2);
  k_finstats<<<1, 512, 0, stream>>>(STC2, gc + 208, bc + 208, WID);

  k_gemm3<<<dim3(782, 2), 256, 0, stream>>>(Z0, Z1, Z2, Y1, W3T, ST, out, ST3);
  k_finstats<<<1, 512, 0, stream>>>(ST3, g3, b3, INC);
  k_final<<<2048, 256, 0, stream>>>(out, ST3 + 4096, ST3 + 4352, x);
}

// Round 6
// 710.396 us; speedup vs baseline: 1.8322x; 1.0188x over previous
//
#include <hip/hip_runtime.h>

#define NPTS 100000
#define INC 256
#define WID 104
#define WSC 416
#define KOFF 27
#define EPSV 1e-5f

typedef unsigned short u16;
typedef float f32x4 __attribute__((ext_vector_type(4)));
typedef short s16x8 __attribute__((ext_vector_type(8)));

__device__ __forceinline__ u16 f2bf(float f) {
  unsigned u = __builtin_bit_cast(unsigned, f);
  u += 0x7FFFu + ((u >> 16) & 1u);
  return (u16)(u >> 16);
}
__device__ __forceinline__ float bf2f(u16 h) {
  unsigned u = ((unsigned)h) << 16;
  return __builtin_bit_cast(float, u);
}
__device__ __forceinline__ void mfma16(f32x4& d, s16x8 a, s16x8 b) {
  asm("v_mfma_f32_16x16x32_bf16 %0, %1, %2, %0" : "+v"(d) : "v"(a), "v"(b));
}
__device__ __forceinline__ void rawbar() {
  __builtin_amdgcn_s_barrier();
  __builtin_amdgcn_sched_barrier(0);
}

// stats region (floats): ST1 banks 8x832 @0; STC_p banks 8x208 @6656+p*1664; ST3 banks 8x512 @11648
#define ST1_OFF 0
#define STC_OFF 6656
#define STC_SZ 1664
#define ST3_OFF 11648
#define ST_TOTAL 15744

#define SPAD 128   // SPX row stride (elems) = 256B aligned

// ---------------- weight prep ----------------
__global__ __launch_bounds__(256) void k_prep_w1w3(const float* __restrict__ w1,
    const float* __restrict__ w3, u16* __restrict__ w1t, u16* __restrict__ w3t) {
  int i = blockIdx.x * 256 + threadIdx.x;
  if (i < 416 * 256) {
    int n = i >> 8, k = i & 255;
    w1t[i] = f2bf(w1[(size_t)k * WSC + n]);
  } else if (i < 2 * 416 * 256) {
    int o = i - 416 * 256;
    int n = o / WSC, k = o - n * WSC;
    w3t[o] = f2bf(w3[(size_t)k * INC + n]);
  }
}

// WCT: [branch*27+k][112 rows=out-col (8 pad)][104 cols=k-in] bf16
__global__ __launch_bounds__(256) void k_prep_wc(const float* __restrict__ wc,
                                                 u16* __restrict__ wct) {
  __shared__ float w[WID * WID];
  int b = blockIdx.x, t = threadIdx.x;
  const float* s = wc + (size_t)b * WID * WID;
  for (int i = t; i < WID * WID; i += 256) w[i] = s[i];
  __syncthreads();
  u16* d = wct + (size_t)b * 112 * WID;
  for (int o = t; o < 112 * WID; o += 256) {
    int n = o / WID, kin = o - n * WID;
    d[o] = f2bf((n < WID) ? w[kin * WID + n] : 0.f);
  }
}

__global__ void k_init(float* __restrict__ st, u16* __restrict__ spxp) {
  const s16x8 hz = {0, 0, 0, 0, 0, 0, 0, 0};
  int i = blockIdx.x * 256 + threadIdx.x;
  if (i < ST_TOTAL) st[i] = 0.f;
  for (int task = i; task < (NPTS + 1) * 3; task += gridDim.x * 256) {
    int r = task / 3, c = task - 3 * r;
    *(s16x8*)(spxp + (size_t)r * SPAD + (13 + c) * 8) = hz;
  }
  if (blockIdx.x == 0 && threadIdx.x < 13)
    *(s16x8*)(spxp + (size_t)NPTS * SPAD + threadIdx.x * 8) = hz;
}

// ---------------- x -> bf16 ----------------
__global__ __launch_bounds__(256) void k_xbf(const float* __restrict__ x,
                                             u16* __restrict__ xb) {
  const int total = NPTS * INC / 8;
  for (int i = blockIdx.x * 256 + threadIdx.x; i < total; i += gridDim.x * 256) {
    const f32x4* s = (const f32x4*)(x + (size_t)i * 8);
    f32x4 v0 = s[0], v1 = s[1];
    s16x8 h;
#pragma unroll
    for (int j = 0; j < 4; ++j) { h[j] = (short)f2bf(v0[j]); h[4 + j] = (short)f2bf(v1[j]); }
    *(s16x8*)(xb + (size_t)i * 8) = h;
  }
}

// ---------------- GEMM1: xb @ W1 -> Y1 slabs [4][N][104] + banked stats ----------------
__global__ __launch_bounds__(256) void k_gemm1(const u16* __restrict__ xb,
    const u16* __restrict__ w1t, u16* __restrict__ ys, float* __restrict__ stats) {
  const int n = blockIdx.x, xcd = n & 7, sgrp = n >> 3;
  const int cb = sgrp & 3, q = sgrp >> 2;
  const int rowbase = (xcd + 8 * q) * 128;
  if (rowbase >= NPTS) return;
  __shared__ char Al[128 * 128];
  __shared__ char Bl[112 * 128];
  const int t = threadIdx.x;
  const int lane = t & 63, wv = t >> 6, lr = lane & 15, lg = lane >> 4;
  const f32x4 fz = {0.f, 0.f, 0.f, 0.f};
  const s16x8 hz = {0, 0, 0, 0, 0, 0, 0, 0};
  f32x4 acc[2][7];
#pragma unroll
  for (int i = 0; i < 2; ++i)
#pragma unroll
    for (int j = 0; j < 7; ++j) acc[i][j] = fz;
  s16x8 pa[4], pb[4];

  auto issue = [&](int st) {
#pragma unroll
    for (int it = 0; it < 4; ++it) {
      int task = t + it * 256, r = task >> 3, c = task & 7, gr = rowbase + r;
      pa[it] = hz;
      if (gr < NPTS) pa[it] = *(const s16x8*)(xb + (size_t)gr * INC + st * 64 + c * 8);
      pb[it] = hz;
      if (task < 832)
        pb[it] = *(const s16x8*)(w1t + (size_t)(cb * WID + r) * INC + st * 64 + c * 8);
    }
  };
  auto writeT = [&]() {
#pragma unroll
    for (int it = 0; it < 4; ++it) {
      int task = t + it * 256, r = task >> 3, c = task & 7;
      *(s16x8*)(Al + ((r * 128 + c * 16) ^ ((r & 7) << 4))) = pa[it];
      if (task < 896) *(s16x8*)(Bl + ((r * 128 + c * 16) ^ ((r & 7) << 4))) = pb[it];
    }
  };
  auto compute = [&]() {
#pragma unroll
    for (int kc = 0; kc < 2; ++kc) {
      int co = kc * 64 + lg * 16;
      s16x8 a[2], b[7];
#pragma unroll
      for (int mt = 0; mt < 2; ++mt) {
        int r = wv * 32 + mt * 16 + lr;
        a[mt] = *(const s16x8*)(Al + ((r * 128 + co) ^ ((r & 7) << 4)));
      }
#pragma unroll
      for (int ct = 0; ct < 7; ++ct) {
        int r = ct * 16 + lr;
        b[ct] = *(const s16x8*)(Bl + ((r * 128 + co) ^ ((r & 7) << 4)));
      }
#pragma unroll
      for (int mt = 0; mt < 2; ++mt)
#pragma unroll
        for (int ct = 0; ct < 7; ++ct) mfma16(acc[mt][ct], a[mt], b[ct]);
    }
  };

  issue(0);
  for (int st = 0; st < 4; ++st) {
    writeT();
    __syncthreads();
    if (st < 3) issue(st + 1);
    compute();
    if (st < 3) rawbar();
  }
  __syncthreads();
  float* S = (float*)Al;
#pragma unroll
  for (int ct = 0; ct < 7; ++ct) {
    float s = 0.f, qq = 0.f;
#pragma unroll
    for (int mt = 0; mt < 2; ++mt)
#pragma unroll
      for (int j = 0; j < 4; ++j) { float v = acc[mt][ct][j]; s += v; qq += v * v; }
    s += __shfl_xor(s, 16); s += __shfl_xor(s, 32);
    qq += __shfl_xor(qq, 16); qq += __shfl_xor(qq, 32);
    if (lane < 16) {
      S[wv * 224 + ct * 16 + lane] = s;
      S[wv * 224 + 112 + ct * 16 + lane] = qq;
    }
  }
  __syncthreads();
  if (t < 224) {
    float v = S[t] + S[224 + t] + S[448 + t] + S[672 + t];
    int cl = (t < 112) ? t : t - 112;
    if (cl < WID) {
      float* base = stats + (sgrp & 7) * 832;
      atomicAdd(base + ((t < 112) ? 0 : WSC) + cb * WID + cl, v);
    }
  }
  __syncthreads();
#pragma unroll
  for (int mt = 0; mt < 2; ++mt)
#pragma unroll
    for (int ct = 0; ct < 7; ++ct)
#pragma unroll
      for (int j = 0; j < 4; ++j) {
        int r = rowbase + wv * 32 + mt * 16 + lg * 4 + j;
        int cl = ct * 16 + lr;
        if (r < NPTS && cl < WID)
          ys[((size_t)cb * NPTS + r) * WID + cl] = f2bf(acc[mt][ct][j]);
      }
}

// ---------------- sparse conv: direct-frag rolling gather, B in LDS ----------------
__global__ __launch_bounds__(256) void k_conv(const u16* __restrict__ src,
    const int* __restrict__ nbr, const u16* __restrict__ wct,
    u16* __restrict__ z, float* __restrict__ stats) {
  __shared__ char Bl[112 * 208 + 64];   // +64 OOB pad for kc3/lg>0 reads (A=0 there)
  const int t = threadIdx.x, rowbase = blockIdx.x * 128;
  const int lane = t & 63, wv = t >> 6, lr = lane & 15, lg = lane >> 4;
  const f32x4 fz = {0.f, 0.f, 0.f, 0.f};
  f32x4 acc[2][7];
#pragma unroll
  for (int i = 0; i < 2; ++i)
#pragma unroll
    for (int j = 0; j < 7; ++j) acc[i][j] = fz;
  s16x8 pa[2][4], pb[6];

  const int rm0 = rowbase + wv * 32 + lr, rm1 = rm0 + 16;
  const bool ok0 = rm0 < NPTS, ok1 = rm1 < NPTS;
  const int* np0 = nbr + (size_t)(ok0 ? rm0 : 0) * KOFF;
  const int* np1 = nbr + (size_t)(ok1 ? rm1 : 0) * KOFF;
  int in0, in1;

  auto loadB = [&](int k) {
#pragma unroll
    for (int it = 0; it < 6; ++it) {
      int task = t + it * 256;
      if (task < 1456) {
        int r = task / 13, c = task - 13 * r;
        pb[it] = *(const s16x8*)(wct + ((size_t)k * 112 + r) * WID + c * 8);
      }
    }
  };
  auto writeB = [&]() {
#pragma unroll
    for (int it = 0; it < 6; ++it) {
      int task = t + it * 256;
      if (task < 1456) {
        int r = task / 13, c = task - 13 * r;
        *(s16x8*)(Bl + r * 208 + c * 16) = pb[it];
      }
    }
  };

  { // prologue: gather k=0 frags, stage B0, prefetch idx k=1
    int i0 = ok0 ? np0[0] : NPTS, i1 = ok1 ? np1[0] : NPTS;
#pragma unroll
    for (int kc = 0; kc < 4; ++kc) {
      pa[0][kc] = *(const s16x8*)(src + (size_t)i0 * SPAD + kc * 32 + lg * 8);
      pa[1][kc] = *(const s16x8*)(src + (size_t)i1 * SPAD + kc * 32 + lg * 8);
    }
    loadB(0);
    in0 = ok0 ? np0[1] : NPTS;
    in1 = ok1 ? np1[1] : NPTS;
  }

  for (int k = 0; k < KOFF; ++k) {
    writeB();
    __syncthreads();
    if (k < KOFF - 1) loadB(k + 1);
    const bool more = k < KOFF - 1;
#pragma unroll
    for (int kc = 0; kc < 4; ++kc) {
      s16x8 bf[7];
#pragma unroll
      for (int ct = 0; ct < 7; ++ct)
        bf[ct] = *(const s16x8*)(Bl + (ct * 16 + lr) * 208 + kc * 64 + lg * 16);
#pragma unroll
      for (int ct = 0; ct < 7; ++ct) {
        mfma16(acc[0][ct], pa[0][kc], bf[ct]);
        mfma16(acc[1][ct], pa[1][kc], bf[ct]);
      }
      if (more) {  // re-gather this kc slot for k+1 (consumed next phase)
        pa[0][kc] = *(const s16x8*)(src + (size_t)in0 * SPAD + kc * 32 + lg * 8);
        pa[1][kc] = *(const s16x8*)(src + (size_t)in1 * SPAD + kc * 32 + lg * 8);
      }
    }
    if (k < KOFF - 2) {
      in0 = ok0 ? np0[k + 2] : NPTS;
      in1 = ok1 ? np1[k + 2] : NPTS;
    }
    rawbar();
  }

  __syncthreads();
  float* S = (float*)Bl;
#pragma unroll
  for (int ct = 0; ct < 7; ++ct) {
    float s = 0.f, qq = 0.f;
#pragma unroll
    for (int mt = 0; mt < 2; ++mt)
#pragma unroll
      for (int j = 0; j < 4; ++j) { float v = acc[mt][ct][j]; s += v; qq += v * v; }
    s += __shfl_xor(s, 16); s += __shfl_xor(s, 32);
    qq += __shfl_xor(qq, 16); qq += __shfl_xor(qq, 32);
    if (lane < 16) {
      S[wv * 224 + ct * 16 + lane] = s;
      S[wv * 224 + 112 + ct * 16 + lane] = qq;
    }
  }
  __syncthreads();
  if (t < 224) {
    float v = S[t] + S[224 + t] + S[448 + t] + S[672 + t];
    int cl = (t < 112) ? t : t - 112;
    if (cl < WID) {
      float* base = stats + (blockIdx.x & 7) * 208;
      atomicAdd(base + ((t < 112) ? 0 : WID) + cl, v);
    }
  }
#pragma unroll
  for (int mt = 0; mt < 2; ++mt)
#pragma unroll
    for (int ct = 0; ct < 7; ++ct)
#pragma unroll
      for (int j = 0; j < 4; ++j) {
        int r = rowbase + wv * 32 + mt * 16 + lg * 4 + j;
        int cl = ct * 16 + lr;
        if (r < NPTS && cl < WID)
          z[(size_t)r * WID + cl] = f2bf(acc[mt][ct][j]);
      }
}

// ---------------- GEMM3: BN'd cat @ W3 -> OB bf16 + banked stats ----------------
__global__ __launch_bounds__(256) void k_gemm3(const u16* __restrict__ z0,
    const u16* __restrict__ z1, const u16* __restrict__ z2, const u16* __restrict__ ys,
    const u16* __restrict__ w3t, const float* __restrict__ ST,
    const float* __restrict__ gcp, const float* __restrict__ bcp,
    const float* __restrict__ g1, const float* __restrict__ b1,
    u16* __restrict__ ob, float* __restrict__ st3) {
  const int n = blockIdx.x, xcd = n & 7, sgrp = n >> 3;
  const int cb = sgrp & 1, q = sgrp >> 1;
  const int rowbase = (xcd + 8 * q) * 128;
  if (rowbase >= NPTS) return;
  __shared__ char Al[128 * 128];
  __shared__ char Bl[128 * 128];
  __shared__ float sscl[416], ssft[416];
  const int t = threadIdx.x;
  const int lane = t & 63, wv = t >> 6, lr = lane & 15, lg = lane >> 4;
  const int wr = wv >> 1, wc = wv & 1;
  const f32x4 fz = {0.f, 0.f, 0.f, 0.f};
  const s16x8 hz = {0, 0, 0, 0, 0, 0, 0, 0};
  const u16* ys3 = ys + (size_t)3 * NPTS * WID;
  for (int i = t; i < 416; i += 256) {
    float s = 0.f, qq = 0.f, gg, bb;
    if (i < 312) {
      int p = i / 104, c = i - p * 104;
      const float* base = ST + STC_OFF + p * STC_SZ;
#pragma unroll
      for (int bk = 0; bk < 8; ++bk) { s += base[bk * 208 + c]; qq += base[bk * 208 + 104 + c]; }
      gg = gcp[i]; bb = bcp[i];
    } else {
#pragma unroll
      for (int bk = 0; bk < 8; ++bk) { s += ST[bk * 832 + i]; qq += ST[bk * 832 + 416 + i]; }
      gg = g1[i]; bb = b1[i];
    }
    float m = s * (1.f / NPTS);
    float var = qq * (1.f / NPTS) - m * m;
    float rs = rsqrtf(var + EPSV);
    float sc = rs * gg;
    sscl[i] = sc; ssft[i] = bb - m * sc;
  }
  f32x4 acc[4][4];
#pragma unroll
  for (int i = 0; i < 4; ++i)
#pragma unroll
    for (int j = 0; j < 4; ++j) acc[i][j] = fz;
  s16x8 pa[4], pb[4];

  auto issue = [&](int st) {
#pragma unroll
    for (int it = 0; it < 4; ++it) {
      int task = t + it * 256, r = task >> 3, c = task & 7;
      int gr = rowbase + r, gq = st * 8 + c;
      pa[it] = hz;
      if (gr < NPTS && gq < 52) {
        int p = gq / 13, cc8 = (gq - p * 13) * 8;
        const u16* s = (p == 0) ? z0 + (size_t)gr * WID + cc8
                     : (p == 1) ? z1 + (size_t)gr * WID + cc8
                     : (p == 2) ? z2 + (size_t)gr * WID + cc8
                                : ys3 + (size_t)gr * WID + cc8;
        pa[it] = *(const s16x8*)s;
      }
      int gk = st * 64 + c * 8;
      pb[it] = hz;
      if (gk < WSC) pb[it] = *(const s16x8*)(w3t + (size_t)(cb * 128 + r) * WSC + gk);
    }
  };
  auto writeT = [&](int st) {
#pragma unroll
    for (int it = 0; it < 4; ++it) {
      int task = t + it * 256, r = task >> 3, c = task & 7;
      int gr = rowbase + r, gq = st * 8 + c;
      s16x8 h = hz;
      if (gr < NPTS && gq < 52) {
        int p = gq / 13;
        int colb = p * WID + (gq - p * 13) * 8;
#pragma unroll
        for (int j = 0; j < 8; ++j) {
          float f = fmaxf(bf2f((u16)pa[it][j]) * sscl[colb + j] + ssft[colb + j], 0.f);
          h[j] = (short)f2bf(f);
        }
      }
      *(s16x8*)(Al + ((r * 128 + c * 16) ^ ((r & 7) << 4))) = h;
      *(s16x8*)(Bl + ((r * 128 + c * 16) ^ ((r & 7) << 4))) = pb[it];
    }
  };
  auto compute = [&]() {
#pragma unroll
    for (int kc = 0; kc < 2; ++kc) {
      int co = kc * 64 + lg * 16;
      s16x8 a[4], b[4];
#pragma unroll
      for (int mt = 0; mt < 4; ++mt) {
        int r = wr * 64 + mt * 16 + lr;
        a[mt] = *(const s16x8*)(Al + ((r * 128 + co) ^ ((r & 7) << 4)));
      }
#pragma unroll
      for (int ct = 0; ct < 4; ++ct) {
        int r = wc * 64 + ct * 16 + lr;
        b[ct] = *(const s16x8*)(Bl + ((r * 128 + co) ^ ((r & 7) << 4)));
      }
#pragma unroll
      for (int mt = 0; mt < 4; ++mt)
#pragma unroll
        for (int ct = 0; ct < 4; ++ct) mfma16(acc[mt][ct], a[mt], b[ct]);
    }
  };

  issue(0);
  __syncthreads();
  for (int st = 0; st < 7; ++st) {
    writeT(st);
    __syncthreads();
    if (st < 6) issue(st + 1);
    compute();
    if (st < 6) rawbar();
  }
  __syncthreads();
  float* S = (float*)Al;
#pragma unroll
  for (int ct = 0; ct < 4; ++ct) {
    float s = 0.f, qq = 0.f;
#pragma unroll
    for (int mt = 0; mt < 4; ++mt)
#pragma unroll
      for (int j = 0; j < 4; ++j) { float v = acc[mt][ct][j]; s += v; qq += v * v; }
    s += __shfl_xor(s, 16); s += __shfl_xor(s, 32);
    qq += __shfl_xor(qq, 16); qq += __shfl_xor(qq, 32);
    if (lane < 16) {
      S[wv * 128 + ct * 16 + lane] = s;
      S[wv * 128 + 64 + ct * 16 + lane] = qq;
    }
  }
  __syncthreads();
  {
    float* base = st3 + (sgrp & 7) * 512;
    if (t < 64) atomicAdd(base + cb * 128 + t, S[t] + S[256 + t]);
    else if (t < 128) atomicAdd(base + INC + cb * 128 + (t - 64), S[64 + t - 64] + S[320 + t - 64]);
    else if (t < 192) atomicAdd(base + cb * 128 + 64 + (t - 128), S[128 + t - 128] + S[384 + t - 128]);
    else atomicAdd(base + INC + cb * 128 + 64 + (t - 192), S[192 + t - 192] + S[448 + t - 192]);
  }
#pragma unroll
  for (int mt = 0; mt < 4; ++mt)
#pragma unroll
    for (int ct = 0; ct < 4; ++ct)
#pragma unroll
      for (int j = 0; j < 4; ++j) {
        int r = rowbase + wr * 64 + mt * 16 + lg * 4 + j;
        int col = cb * 128 + wc * 64 + ct * 16 + lr;
        if (r < NPTS) ob[(size_t)r * INC + col] = f2bf(acc[mt][ct][j]);
      }
}

// ---------------- mix: SPX = [relu(bnc(Z)) +] relu(bn1(Y slab)), fused stats ----------------
template <int HASZ>
__global__ __launch_bounds__(256) void k_mix(const u16* __restrict__ ys, int slab,
    const float* __restrict__ ST, int yoff,
    const float* __restrict__ g1, const float* __restrict__ b1,
    const u16* __restrict__ z, const float* __restrict__ stc,
    const float* __restrict__ gcb, const float* __restrict__ bcb,
    u16* __restrict__ spx) {
  __shared__ float s1c[104], f1c[104], szc[104], fzc[104];
  const int t = threadIdx.x;
  if (t < 104) {
    float s = 0.f, q = 0.f;
#pragma unroll
    for (int bk = 0; bk < 8; ++bk) { s += ST[bk * 832 + yoff + t]; q += ST[bk * 832 + 416 + yoff + t]; }
    float m = s * (1.f / NPTS);
    float var = q * (1.f / NPTS) - m * m;
    float rs = rsqrtf(var + EPSV);
    float sc = rs * g1[yoff + t];
    s1c[t] = sc; f1c[t] = b1[yoff + t] - m * sc;
  } else if (HASZ && t >= 128 && t < 232) {
    int c = t - 128;
    float s = 0.f, q = 0.f;
#pragma unroll
    for (int bk = 0; bk < 8; ++bk) { s += stc[bk * 208 + c]; q += stc[bk * 208 + 104 + c]; }
    float m = s * (1.f / NPTS);
    float var = q * (1.f / NPTS) - m * m;
    float rs = rsqrtf(var + EPSV);
    float sc = rs * gcb[c];
    szc[c] = sc; fzc[c] = bcb[c] - m * sc;
  }
  __syncthreads();
  const u16* yb = ys + (size_t)slab * NPTS * WID;
  const int total = NPTS * 13;
  for (int i = blockIdx.x * 256 + t; i < total; i += gridDim.x * 256) {
    int r = i / 13, cc = i - r * 13;
    s16x8 y = *(const s16x8*)(yb + (size_t)r * WID + cc * 8);
    s16x8 zv;
    if (HASZ) zv = *(const s16x8*)(z + (size_t)r * WID + cc * 8);
    s16x8 o;
#pragma unroll
    for (int j = 0; j < 8; ++j) {
      int c = cc * 8 + j;
      float f = fmaxf(bf2f((u16)y[j]) * s1c[c] + f1c[c], 0.f);
      if (HASZ) f += fmaxf(bf2f((u16)zv[j]) * szc[c] + fzc[c], 0.f);
      o[j] = (short)f2bf(f);
    }
    *(s16x8*)(spx + (size_t)r * SPAD + cc * 8) = o;
  }
}

// ---------------- final: out = relu(bn3(ob) + xb), fused stats ----------------
__global__ __launch_bounds__(256) void k_final(const u16* __restrict__ ob,
    const u16* __restrict__ xb, const float* __restrict__ ST3,
    const float* __restrict__ g3, const float* __restrict__ b3,
    float* __restrict__ out) {
  __shared__ float sc3[256], sf3[256];
  const int t = threadIdx.x;
  {
    float s = 0.f, q = 0.f;
#pragma unroll
    for (int bk = 0; bk < 8; ++bk) { s += ST3[bk * 512 + t]; q += ST3[bk * 512 + 256 + t]; }
    float m = s * (1.f / NPTS);
    float var = q * (1.f / NPTS) - m * m;
    float rs = rsqrtf(var + EPSV);
    float sc = rs * g3[t];
    sc3[t] = sc; sf3[t] = b3[t] - m * sc;
  }
  __syncthreads();
  const int total = NPTS * 32;
  for (int i = blockIdx.x * 256 + t; i < total; i += gridDim.x * 256) {
    int r = i >> 5, cc = i & 31;
    s16x8 o = *(const s16x8*)(ob + (size_t)r * INC + cc * 8);
    s16x8 xv = *(const s16x8*)(xb + (size_t)r * INC + cc * 8);
    f32x4 v0, v1;
#pragma unroll
    for (int j = 0; j < 4; ++j) {
      int c = cc * 8 + j;
      v0[j] = fmaxf(bf2f((u16)o[j]) * sc3[c] + sf3[c] + bf2f((u16)xv[j]), 0.f);
    }
#pragma unroll
    for (int j = 0; j < 4; ++j) {
      int c = cc * 8 + 4 + j;
      v1[j] = fmaxf(bf2f((u16)o[4 + j]) * sc3[c] + sf3[c] + bf2f((u16)xv[4 + j]), 0.f);
    }
    f32x4* dp = (f32x4*)(out + (size_t)r * INC + cc * 8);
    dp[0] = v0; dp[1] = v1;
  }
}

// ---------------- launch ----------------
extern "C" void kernel_launch(void* const* d_in, const int* in_sizes, int n_in,
                              void* d_out, int out_size, void* d_ws, size_t ws_size,
                              hipStream_t stream) {
  const float* x  = (const float*)d_in[0];
  const int* nbr  = (const int*)d_in[1];
  const float* W1 = (const float*)d_in[2];
  const float* g1 = (const float*)d_in[3];
  const float* b1 = (const float*)d_in[4];
  const float* Wc = (const float*)d_in[5];
  const float* gc = (const float*)d_in[6];
  const float* bc = (const float*)d_in[7];
  const float* W3 = (const float*)d_in[8];
  const float* g3 = (const float*)d_in[9];
  const float* b3 = (const float*)d_in[10];
  float* out = (float*)d_out;

  char* ws = (char*)d_ws;
  size_t off = 0;
  auto alloc = [&](size_t nbytes) {
    char* p = ws + off;
    off += (nbytes + 255) & ~(size_t)255;
    return p;
  };
  u16* W1T = (u16*)alloc(416 * 256 * 2);
  u16* W3T = (u16*)alloc(256 * 416 * 2);
  u16* WCT = (u16*)alloc((size_t)3 * 27 * 112 * 104 * 2);
  u16* XB  = (u16*)alloc((size_t)NPTS * INC * 2);
  u16* Y1S = (u16*)alloc((size_t)4 * NPTS * WID * 2);
  u16* Z0  = (u16*)alloc((size_t)NPTS * WID * 2);
  u16* Z1  = (u16*)alloc((size_t)NPTS * WID * 2);
  u16* Z2  = (u16*)alloc((size_t)NPTS * WID * 2);
  u16* OB  = (u16*)alloc((size_t)NPTS * INC * 2);
  u16* SPX = (u16*)alloc((size_t)(NPTS + 1) * SPAD * 2);
  float* ST = (float*)alloc(ST_TOTAL * 4);
  float* ST1  = ST + ST1_OFF;
  float* STC0 = ST + STC_OFF;
  float* STC1 = ST + STC_OFF + STC_SZ;
  float* STC2 = ST + STC_OFF + 2 * STC_SZ;
  float* ST3  = ST + ST3_OFF;

  k_prep_w1w3<<<832, 256, 0, stream>>>(W1, W3, W1T, W3T);
  k_prep_wc<<<81, 256, 0, stream>>>(Wc, WCT);
  k_init<<<256, 256, 0, stream>>>(ST, SPX);
  k_xbf<<<2048, 256, 0, stream>>>(x, XB);

  k_gemm1<<<3136, 256, 0, stream>>>(XB, W1T, Y1S, ST1);

  const size_t WCL = (size_t)27 * 112 * WID;
  // branch 0
  k_mix<0><<<2048, 256, 0, stream>>>(Y1S, 0, ST1, 0, g1, b1,
                                     nullptr, nullptr, nullptr, nullptr, SPX);
  k_conv<<<782, 256, 0, stream>>>(SPX, nbr, WCT, Z0, STC0);
  // branch 1
  k_mix<1><<<2048, 256, 0, stream>>>(Y1S, 1, ST1, 104, g1, b1,
                                     Z0, STC0, gc, bc, SPX);
  k_conv<<<782, 256, 0, stream>>>(SPX, nbr, WCT + WCL, Z1, STC1);
  // branch 2
  k_mix<1><<<2048, 256, 0, stream>>>(Y1S, 2, ST1, 208, g1, b1,
                                     Z1, STC1, gc + 104, bc + 104, SPX);
  k_conv<<<782, 256, 0, stream>>>(SPX, nbr, WCT + 2 * WCL, Z2, STC2);

  k_gemm3<<<1568, 256, 0, stream>>>(Z0, Z1, Z2, Y1S, W3T, ST, gc, bc, g1, b1, OB, ST3);
  k_final<<<2048, 256, 0, stream>>>(OB, XB, ST3, g3, b3, out);
}